// Round 16
// baseline (292.093 us; speedup 1.0000x reference)
//
#include <hip/hip_runtime.h>
#include <hip/hip_bf16.h>

#define CC 256
#define CMM 32
#define KW 7
#define KK 49
#define PADW 3
#define HH 56
#define WW 56
#define HP 62
#define LP 3844   // 62*62
#define LL 3136   // 56*56
#define BB 2
#define MM 8
#define MIDW 16
#define AREP 16   // diagnostic repeat on attn ONLY

typedef __attribute__((ext_vector_type(8))) short bf16x8;
typedef __attribute__((ext_vector_type(4))) float f32x4;
typedef __attribute__((ext_vector_type(8))) unsigned short us8_t;
typedef __attribute__((ext_vector_type(4))) unsigned short us4_t;

__device__ inline short bfr(float f) {   // f32 -> bf16 bits, RNE
  unsigned int u = __builtin_bit_cast(unsigned int, f);
  u += 0x7fffu + ((u >> 16) & 1u);
  return (short)(u >> 16);
}
__device__ inline float bf2f(short h) {
  return __builtin_bit_cast(float, ((unsigned int)(unsigned short)h) << 16);
}

// ---------------- k/q 1x1 conv as bf16 MFMA GEMM (R14, unchanged) ----------
__global__ void __launch_bounds__(256) kq_kernel(
    const float* __restrict__ x,
    const float* __restrict__ k_w, const float* __restrict__ k_b,
    const float* __restrict__ q_w, const float* __restrict__ q_b,
    float* __restrict__ km, float* __restrict__ qm) {
  __shared__ unsigned short bsT[2][64][40];
  int t = threadIdx.x;
  int lane = t & 63;
  int w = t >> 6;
  int px0 = blockIdx.x * 64;
  int b = blockIdx.z;
  int l15 = lane & 15;
  int hi = lane >> 4;

  int oc_a = w * 16 + l15;
  const float* wrow = ((oc_a < CMM) ? (k_w + (size_t)oc_a * CC)
                                    : (q_w + (size_t)(oc_a - CMM) * CC)) + hi * 8;
  bf16x8 ah[8], al[8];
  #pragma unroll
  for (int s = 0; s < 8; ++s) {
    f32x4 w0 = *(const f32x4*)(wrow + s * 32);
    f32x4 w1 = *(const f32x4*)(wrow + s * 32 + 4);
    bf16x8 h, l;
    #pragma unroll
    for (int j = 0; j < 4; ++j) {
      short hb0 = bfr(w0[j]); h[j] = hb0;     l[j] = bfr(w0[j] - bf2f(hb0));
      short hb1 = bfr(w1[j]); h[j + 4] = hb1; l[j + 4] = bfr(w1[j] - bf2f(hb1));
    }
    ah[s] = h; al[s] = l;
  }

  int spx = t & 63;
  int skb = (t >> 6) * 8;
  const float* xg = x + (size_t)b * CC * LL + px0 + spx;

  {
    float fv[8];
    #pragma unroll
    for (int j = 0; j < 8; ++j) fv[j] = xg[(size_t)(skb + j) * LL];
    us8_t hv;
    #pragma unroll
    for (int j = 0; j < 8; ++j) hv[j] = (unsigned short)bfr(fv[j]);
    *(us8_t*)&bsT[0][spx][skb] = hv;
  }

  f32x4 acc[4];
  #pragma unroll
  for (int q = 0; q < 4; ++q) acc[q] = {0.f, 0.f, 0.f, 0.f};

  for (int s = 0; s < 8; ++s) {
    __syncthreads();
    float fv[8];
    if (s < 7) {
      #pragma unroll
      for (int j = 0; j < 8; ++j)
        fv[j] = xg[(size_t)((s + 1) * 32 + skb + j) * LL];
    }
    int cur = s & 1;
    #pragma unroll
    for (int q = 0; q < 4; ++q) {
      bf16x8 bv = *(const bf16x8*)&bsT[cur][q * 16 + l15][hi * 8];
      acc[q] = __builtin_amdgcn_mfma_f32_16x16x32_bf16(ah[s], bv, acc[q], 0, 0, 0);
      acc[q] = __builtin_amdgcn_mfma_f32_16x16x32_bf16(al[s], bv, acc[q], 0, 0, 0);
    }
    if (s < 7) {
      us8_t hv;
      #pragma unroll
      for (int j = 0; j < 8; ++j) hv[j] = (unsigned short)bfr(fv[j]);
      *(us8_t*)&bsT[cur ^ 1][spx][skb] = hv;
    }
  }

  #pragma unroll
  for (int q = 0; q < 4; ++q) {
    #pragma unroll
    for (int rr = 0; rr < 4; ++rr) {
      int oc = w * 16 + hi * 4 + rr;
      int px = px0 + q * 16 + l15;
      if (oc < CMM)
        km[((size_t)b * CMM + oc) * LL + px] = acc[q][rr] + k_b[oc];
      else
        qm[((size_t)b * CMM + (oc - CMM)) * LL + px] = acc[q][rr] + q_b[oc - CMM];
    }
  }
}

// ---------------- fused QK * rowwise-softmax * PV (R14; AREP diagnostic) ----
__global__ void __launch_bounds__(512) attn_kernel(
    const float* __restrict__ x, const float* __restrict__ km,
    const float* __restrict__ qm,
    const float* __restrict__ gp_w1, const float* __restrict__ gp_b1,
    const float* __restrict__ gp_w2, const float* __restrict__ gp_b2,
    const float* __restrict__ k_b,
    __hip_bfloat16* __restrict__ pre) {
  __shared__ float xs[MM][10][64];
  __shared__ float ks[10][64];
  __shared__ float gs[KK];
  int t = threadIdx.x;
  int cm = blockIdx.y;
  int b = blockIdx.z;
  int y0 = blockIdx.x * 4;

  if (t < KK) {
    int i = t / KW, j = t % KW;
    float xpos = (float)(j - PADW), ypos = (float)(PADW - i);
    float a = gp_b2[cm];
    #pragma unroll
    for (int m = 0; m < MIDW; ++m) {
      float h = fmaxf(gp_w1[2 * m] * xpos + gp_w1[2 * m + 1] * ypos + gp_b1[m], 0.f);
      a = fmaf(gp_w2[cm * MIDW + m], h, a);
    }
    gs[t] = a;
  }
  float kb_cm = k_b[cm];
  const float* kmb = km + ((size_t)b * CMM + cm) * LL;
  const float* xg = x + (size_t)b * CC * LL;

  int w = t >> 6, lane = t & 63;
  int wr = w & 3;
  int mb = (w >> 2) * 4;
  int y = y0 + wr;
  int c = lane;
  int ce = (c < WW) ? c : (WW - 1);
  bool act = (c < WW);

  for (int rep = 0; rep < AREP; ++rep) {
    for (int e = t; e < 640; e += 512) {
      int ri = e >> 6, cl = e & 63;
      int rp = y0 + ri;
      bool inner = (rp >= PADW && rp < PADW + HH && cl >= PADW && cl < PADW + WW);
      ks[ri][cl] = inner ? kmb[(rp - PADW) * WW + (cl - PADW)] : kb_cm;
    }
    for (int e = t; e < 640; e += 512) {
      int ri = e >> 6, cl = e & 63;
      int ir = y0 - PADW + ri;
      int ic = cl - PADW;
      bool ok = (ir >= 0 && ir < HH && ic >= 0 && ic < WW);
      int off = ok ? (ir * WW + ic) : 0;
      #pragma unroll
      for (int m = 0; m < MM; ++m)
        xs[m][ri][cl] = ok ? xg[(size_t)(m * CMM + cm) * LL + off] : 0.f;
    }
    __syncthreads();

    float qc = qm[((size_t)b * CMM + cm) * LL + y * WW + ce];
    float acc[4] = {0.f, 0.f, 0.f, 0.f};
    #pragma unroll
    for (int i = 0; i < KW; ++i) {
      int row = wr + i;
      float s[KW];
      #pragma unroll
      for (int j = 0; j < KW; ++j)
        s[j] = fmaf(ks[row][ce + j], qc, gs[i * KW + j]);
      float mx = fmaxf(fmaxf(fmaxf(s[0], s[1]), fmaxf(s[2], s[3])),
                       fmaxf(fmaxf(s[4], s[5]), s[6]));
      float sum = 0.f;
      #pragma unroll
      for (int j = 0; j < KW; ++j) { s[j] = __expf(s[j] - mx); sum += s[j]; }
      float inv = __builtin_amdgcn_rcpf(sum);
      #pragma unroll
      for (int mm = 0; mm < 4; ++mm) {
        const float* xr = &xs[mb + mm][row][ce];
        float dot = s[0] * xr[0];
        dot = fmaf(s[1], xr[1], dot);
        dot = fmaf(s[2], xr[2], dot);
        dot = fmaf(s[3], xr[3], dot);
        dot = fmaf(s[4], xr[4], dot);
        dot = fmaf(s[5], xr[5], dot);
        dot = fmaf(s[6], xr[6], dot);
        acc[mm] = fmaf(dot, inv, acc[mm]);
      }
    }
    if (act) {
      #pragma unroll
      for (int mm = 0; mm < 4; ++mm)
        pre[((size_t)b * CC + ((mb + mm) * CMM + cm)) * LL + y * WW + c] =
            __float2bfloat16(acc[mm]);
    }
    __syncthreads();
  }
}

// ---------------- final 1x1 conv: bf16 MFMA, transposed LDS B (R14) ---------
__global__ void __launch_bounds__(256) fconv_kernel(
    const unsigned short* __restrict__ preb,
    const float* __restrict__ f_w, const float* __restrict__ f_b,
    float* __restrict__ out) {
  __shared__ unsigned short bsT[2][64][40];
  int t = threadIdx.x;
  int lane = t & 63;
  int w = t >> 6;
  int px0 = blockIdx.x * 64;
  int oc0 = blockIdx.y * 64;
  int b = blockIdx.z;
  int l15 = lane & 15;
  int hi = lane >> 4;

  bf16x8 af[8];
  const float* wrow = f_w + (size_t)(oc0 + w * 16 + l15) * CC + hi * 8;
  #pragma unroll
  for (int s = 0; s < 8; ++s) {
    f32x4 w0 = *(const f32x4*)(wrow + s * 32);
    f32x4 w1 = *(const f32x4*)(wrow + s * 32 + 4);
    bf16x8 a;
    #pragma unroll
    for (int j = 0; j < 4; ++j) { a[j] = bfr(w0[j]); a[j + 4] = bfr(w1[j]); }
    af[s] = a;
  }

  int spx = t & 63;
  int skb = (t >> 6) * 8;
  const unsigned short* pg = preb + (size_t)b * CC * LL + px0 + spx;

  {
    us8_t hv;
    #pragma unroll
    for (int j = 0; j < 8; ++j) hv[j] = pg[(size_t)(skb + j) * LL];
    *(us8_t*)&bsT[0][spx][skb] = hv;
  }

  f32x4 acc[4];
  #pragma unroll
  for (int q = 0; q < 4; ++q) acc[q] = {0.f, 0.f, 0.f, 0.f};

  for (int s = 0; s < 8; ++s) {
    __syncthreads();
    unsigned short vn[8];
    if (s < 7) {
      #pragma unroll
      for (int j = 0; j < 8; ++j)
        vn[j] = pg[(size_t)((s + 1) * 32 + skb + j) * LL];
    }
    int cur = s & 1;
    #pragma unroll
    for (int q = 0; q < 4; ++q) {
      bf16x8 bv = *(const bf16x8*)&bsT[cur][q * 16 + l15][hi * 8];
      acc[q] = __builtin_amdgcn_mfma_f32_16x16x32_bf16(af[s], bv, acc[q], 0, 0, 0);
    }
    if (s < 7) {
      us8_t hv;
      #pragma unroll
      for (int j = 0; j < 8; ++j) hv[j] = vn[j];
      *(us8_t*)&bsT[cur ^ 1][spx][skb] = hv;
    }
  }

  #pragma unroll
  for (int q = 0; q < 4; ++q) {
    #pragma unroll
    for (int rr = 0; rr < 4; ++rr) {
      int oc = oc0 + w * 16 + hi * 4 + rr;
      out[((size_t)b * CC + oc) * LL + px0 + q * 16 + l15] = acc[q][rr] + f_b[oc];
    }
  }
}

extern "C" void kernel_launch(void* const* d_in, const int* in_sizes, int n_in,
                              void* d_out, int out_size, void* d_ws, size_t ws_size,
                              hipStream_t stream) {
  const float* x     = (const float*)d_in[0];
  const float* k_w   = (const float*)d_in[1];
  const float* k_b   = (const float*)d_in[2];
  const float* q_w   = (const float*)d_in[3];
  const float* q_b   = (const float*)d_in[4];
  const float* gp_w1 = (const float*)d_in[5];
  const float* gp_b1 = (const float*)d_in[6];
  const float* gp_w2 = (const float*)d_in[7];
  const float* gp_b2 = (const float*)d_in[8];
  const float* f_w   = (const float*)d_in[9];
  const float* f_b   = (const float*)d_in[10];
  float* out = (float*)d_out;

  float* ws  = (float*)d_ws;
  float* km  = ws;                                   // 2*32*3136 f32 (inner)
  float* qm  = km + (size_t)BB * CMM * LL;
  unsigned short* pre = (unsigned short*)(qm + (size_t)BB * CMM * LL); // bf16

  hipLaunchKernelGGL(kq_kernel, dim3(LL / 64, 1, BB), dim3(256), 0, stream,
                     x, k_w, k_b, q_w, q_b, km, qm);
  hipLaunchKernelGGL(attn_kernel, dim3(HH / 4, CMM, BB), dim3(512), 0, stream,
                     x, km, qm, gp_w1, gp_b1, gp_w2, gp_b2, k_b,
                     (__hip_bfloat16*)pre);
  hipLaunchKernelGGL(fconv_kernel, dim3(LL / 64, CC / 64, BB), dim3(256), 0, stream,
                     pre, f_w, f_b, out);
}

// Round 17
// 43.937 us; speedup vs baseline: 6.6480x; 6.6480x over previous
//
#include <hip/hip_runtime.h>
#include <hip/hip_bf16.h>

#define CC 256
#define CMM 32
#define KW 7
#define KK 49
#define PADW 3
#define HH 56
#define WW 56
#define HP 62
#define LP 3844   // 62*62
#define LL 3136   // 56*56
#define BB 2
#define MM 8
#define MIDW 16

typedef __attribute__((ext_vector_type(8))) short bf16x8;
typedef __attribute__((ext_vector_type(4))) float f32x4;
typedef __attribute__((ext_vector_type(8))) unsigned short us8_t;
typedef __attribute__((ext_vector_type(4))) unsigned short us4_t;

__device__ inline short bfr(float f) {   // f32 -> bf16 bits, RNE
  unsigned int u = __builtin_bit_cast(unsigned int, f);
  u += 0x7fffu + ((u >> 16) & 1u);
  return (short)(u >> 16);
}
__device__ inline float bf2f(short h) {
  return __builtin_bit_cast(float, ((unsigned int)(unsigned short)h) << 16);
}
__device__ inline float ubits(unsigned int u) {
  return __builtin_bit_cast(float, u);
}

// ---------------- k/q 1x1 conv as bf16 MFMA GEMM (R14, unchanged) ----------
__global__ void __launch_bounds__(256) kq_kernel(
    const float* __restrict__ x,
    const float* __restrict__ k_w, const float* __restrict__ k_b,
    const float* __restrict__ q_w, const float* __restrict__ q_b,
    float* __restrict__ km, float* __restrict__ qm) {
  __shared__ unsigned short bsT[2][64][40];
  int t = threadIdx.x;
  int lane = t & 63;
  int w = t >> 6;
  int px0 = blockIdx.x * 64;
  int b = blockIdx.z;
  int l15 = lane & 15;
  int hi = lane >> 4;

  int oc_a = w * 16 + l15;
  const float* wrow = ((oc_a < CMM) ? (k_w + (size_t)oc_a * CC)
                                    : (q_w + (size_t)(oc_a - CMM) * CC)) + hi * 8;
  bf16x8 ah[8], al[8];
  #pragma unroll
  for (int s = 0; s < 8; ++s) {
    f32x4 w0 = *(const f32x4*)(wrow + s * 32);
    f32x4 w1 = *(const f32x4*)(wrow + s * 32 + 4);
    bf16x8 h, l;
    #pragma unroll
    for (int j = 0; j < 4; ++j) {
      short hb0 = bfr(w0[j]); h[j] = hb0;     l[j] = bfr(w0[j] - bf2f(hb0));
      short hb1 = bfr(w1[j]); h[j + 4] = hb1; l[j + 4] = bfr(w1[j] - bf2f(hb1));
    }
    ah[s] = h; al[s] = l;
  }

  int spx = t & 63;
  int skb = (t >> 6) * 8;
  const float* xg = x + (size_t)b * CC * LL + px0 + spx;

  {
    float fv[8];
    #pragma unroll
    for (int j = 0; j < 8; ++j) fv[j] = xg[(size_t)(skb + j) * LL];
    us8_t hv;
    #pragma unroll
    for (int j = 0; j < 8; ++j) hv[j] = (unsigned short)bfr(fv[j]);
    *(us8_t*)&bsT[0][spx][skb] = hv;
  }

  f32x4 acc[4];
  #pragma unroll
  for (int q = 0; q < 4; ++q) acc[q] = {0.f, 0.f, 0.f, 0.f};

  for (int s = 0; s < 8; ++s) {
    __syncthreads();
    float fv[8];
    if (s < 7) {
      #pragma unroll
      for (int j = 0; j < 8; ++j)
        fv[j] = xg[(size_t)((s + 1) * 32 + skb + j) * LL];
    }
    int cur = s & 1;
    #pragma unroll
    for (int q = 0; q < 4; ++q) {
      bf16x8 bv = *(const bf16x8*)&bsT[cur][q * 16 + l15][hi * 8];
      acc[q] = __builtin_amdgcn_mfma_f32_16x16x32_bf16(ah[s], bv, acc[q], 0, 0, 0);
      acc[q] = __builtin_amdgcn_mfma_f32_16x16x32_bf16(al[s], bv, acc[q], 0, 0, 0);
    }
    if (s < 7) {
      us8_t hv;
      #pragma unroll
      for (int j = 0; j < 8; ++j) hv[j] = (unsigned short)bfr(fv[j]);
      *(us8_t*)&bsT[cur ^ 1][spx][skb] = hv;
    }
  }

  #pragma unroll
  for (int q = 0; q < 4; ++q) {
    #pragma unroll
    for (int rr = 0; rr < 4; ++rr) {
      int oc = w * 16 + hi * 4 + rr;
      int px = px0 + q * 16 + l15;
      if (oc < CMM)
        km[((size_t)b * CMM + oc) * LL + px] = acc[q][rr] + k_b[oc];
      else
        qm[((size_t)b * CMM + (oc - CMM)) * LL + px] = acc[q][rr] + q_b[oc - CMM];
    }
  }
}

// ---------------- fused QK * softmax * PV: 1 thread = 1 px x 8 m -----------
// Block 256 thr = 4 waves (wave = band row), lane = col. Softmax ONCE per px
// (exp2-folded, no max — validated R13). x staged bf16 m-packed: PV tap =
// 2x ds_read_b64 + 8 unpack + 8 fma.
__global__ void __launch_bounds__(256) attn_kernel(
    const float* __restrict__ x, const float* __restrict__ km,
    const float* __restrict__ qm,
    const float* __restrict__ gp_w1, const float* __restrict__ gp_b1,
    const float* __restrict__ gp_w2, const float* __restrict__ gp_b2,
    const float* __restrict__ k_b,
    unsigned short* __restrict__ pre) {
  __shared__ unsigned int xlo[10][64][2];   // bf16 pairs (m0,m1),(m2,m3)
  __shared__ unsigned int xhi[10][64][2];   // (m4,m5),(m6,m7)
  __shared__ float ks[10][64];
  __shared__ float gs2[KK];
  const float LOG2E = 1.44269504f;
  int t = threadIdx.x;
  int cm = blockIdx.y;
  int b = blockIdx.z;
  int y0 = blockIdx.x * 4;

  if (t < KK) {
    int i = t / KW, j = t % KW;
    float xpos = (float)(j - PADW), ypos = (float)(PADW - i);
    float a = gp_b2[cm];
    #pragma unroll
    for (int m = 0; m < MIDW; ++m) {
      float h = fmaxf(gp_w1[2 * m] * xpos + gp_w1[2 * m + 1] * ypos + gp_b1[m], 0.f);
      a = fmaf(gp_w2[cm * MIDW + m], h, a);
    }
    gs2[t] = a * LOG2E;
  }
  float kb_cm = k_b[cm];
  const float* kmb = km + ((size_t)b * CMM + cm) * LL;
  for (int e = t; e < 640; e += 256) {
    int ri = e >> 6, cl = e & 63;
    int rp = y0 + ri;
    bool inner = (rp >= PADW && rp < PADW + HH && cl >= PADW && cl < PADW + WW);
    ks[ri][cl] = inner ? kmb[(rp - PADW) * WW + (cl - PADW)] : kb_cm;
  }
  const float* xg = x + (size_t)b * CC * LL;
  for (int e = t; e < 640; e += 256) {
    int ri = e >> 6, cl = e & 63;
    int ir = y0 - PADW + ri;
    int ic = cl - PADW;
    bool ok = (ir >= 0 && ir < HH && ic >= 0 && ic < WW);
    int off = ok ? (ir * WW + ic) : 0;
    unsigned int pk[4];
    #pragma unroll
    for (int mp = 0; mp < 4; ++mp) {
      float v0 = ok ? xg[(size_t)((2 * mp) * CMM + cm) * LL + off] : 0.f;
      float v1 = ok ? xg[(size_t)((2 * mp + 1) * CMM + cm) * LL + off] : 0.f;
      pk[mp] = (unsigned int)(unsigned short)bfr(v0)
             | ((unsigned int)(unsigned short)bfr(v1) << 16);
    }
    *(uint2*)&xlo[ri][cl][0] = make_uint2(pk[0], pk[1]);
    *(uint2*)&xhi[ri][cl][0] = make_uint2(pk[2], pk[3]);
  }
  __syncthreads();

  int w = t >> 6, c = t & 63;
  int y = y0 + w;
  int ce = (c < WW) ? c : (WW - 1);
  bool act = (c < WW);
  float qc = qm[((size_t)b * CMM + cm) * LL + y * WW + ce] * LOG2E;

  float acc[8] = {0.f, 0.f, 0.f, 0.f, 0.f, 0.f, 0.f, 0.f};
  #pragma unroll
  for (int i = 0; i < KW; ++i) {
    int row = w + i;
    float s[KW];
    float sum = 0.f;
    #pragma unroll
    for (int j = 0; j < KW; ++j) {
      s[j] = exp2f(fmaf(ks[row][ce + j], qc, gs2[i * KW + j]));
      sum += s[j];
    }
    float inv = __builtin_amdgcn_rcpf(sum);
    #pragma unroll
    for (int j = 0; j < KW; ++j) {
      float wj = s[j] * inv;
      uint2 lo2 = *(const uint2*)&xlo[row][ce + j][0];
      uint2 hi2 = *(const uint2*)&xhi[row][ce + j][0];
      acc[0] = fmaf(wj, ubits(lo2.x << 16), acc[0]);
      acc[1] = fmaf(wj, ubits(lo2.x & 0xffff0000u), acc[1]);
      acc[2] = fmaf(wj, ubits(lo2.y << 16), acc[2]);
      acc[3] = fmaf(wj, ubits(lo2.y & 0xffff0000u), acc[3]);
      acc[4] = fmaf(wj, ubits(hi2.x << 16), acc[4]);
      acc[5] = fmaf(wj, ubits(hi2.x & 0xffff0000u), acc[5]);
      acc[6] = fmaf(wj, ubits(hi2.y << 16), acc[6]);
      acc[7] = fmaf(wj, ubits(hi2.y & 0xffff0000u), acc[7]);
    }
  }
  if (act) {
    #pragma unroll
    for (int m = 0; m < 8; ++m)
      pre[((size_t)b * CC + (m * CMM + cm)) * LL + y * WW + c] =
          (unsigned short)bfr(acc[m]);
  }
}

// ---------------- final 1x1 conv: bf16 MFMA, transposed LDS B (R14) ---------
__global__ void __launch_bounds__(256) fconv_kernel(
    const unsigned short* __restrict__ preb,
    const float* __restrict__ f_w, const float* __restrict__ f_b,
    float* __restrict__ out) {
  __shared__ unsigned short bsT[2][64][40];
  int t = threadIdx.x;
  int lane = t & 63;
  int w = t >> 6;
  int px0 = blockIdx.x * 64;
  int oc0 = blockIdx.y * 64;
  int b = blockIdx.z;
  int l15 = lane & 15;
  int hi = lane >> 4;

  bf16x8 af[8];
  const float* wrow = f_w + (size_t)(oc0 + w * 16 + l15) * CC + hi * 8;
  #pragma unroll
  for (int s = 0; s < 8; ++s) {
    f32x4 w0 = *(const f32x4*)(wrow + s * 32);
    f32x4 w1 = *(const f32x4*)(wrow + s * 32 + 4);
    bf16x8 a;
    #pragma unroll
    for (int j = 0; j < 4; ++j) { a[j] = bfr(w0[j]); a[j + 4] = bfr(w1[j]); }
    af[s] = a;
  }

  int spx = t & 63;
  int skb = (t >> 6) * 8;
  const unsigned short* pg = preb + (size_t)b * CC * LL + px0 + spx;

  {
    us8_t hv;
    #pragma unroll
    for (int j = 0; j < 8; ++j) hv[j] = pg[(size_t)(skb + j) * LL];
    *(us8_t*)&bsT[0][spx][skb] = hv;
  }

  f32x4 acc[4];
  #pragma unroll
  for (int q = 0; q < 4; ++q) acc[q] = {0.f, 0.f, 0.f, 0.f};

  for (int s = 0; s < 8; ++s) {
    __syncthreads();
    unsigned short vn[8];
    if (s < 7) {
      #pragma unroll
      for (int j = 0; j < 8; ++j)
        vn[j] = pg[(size_t)((s + 1) * 32 + skb + j) * LL];
    }
    int cur = s & 1;
    #pragma unroll
    for (int q = 0; q < 4; ++q) {
      bf16x8 bv = *(const bf16x8*)&bsT[cur][q * 16 + l15][hi * 8];
      acc[q] = __builtin_amdgcn_mfma_f32_16x16x32_bf16(af[s], bv, acc[q], 0, 0, 0);
    }
    if (s < 7) {
      us8_t hv;
      #pragma unroll
      for (int j = 0; j < 8; ++j) hv[j] = vn[j];
      *(us8_t*)&bsT[cur ^ 1][spx][skb] = hv;
    }
  }

  #pragma unroll
  for (int q = 0; q < 4; ++q) {
    #pragma unroll
    for (int rr = 0; rr < 4; ++rr) {
      int oc = oc0 + w * 16 + hi * 4 + rr;
      out[((size_t)b * CC + oc) * LL + px0 + q * 16 + l15] = acc[q][rr] + f_b[oc];
    }
  }
}

extern "C" void kernel_launch(void* const* d_in, const int* in_sizes, int n_in,
                              void* d_out, int out_size, void* d_ws, size_t ws_size,
                              hipStream_t stream) {
  const float* x     = (const float*)d_in[0];
  const float* k_w   = (const float*)d_in[1];
  const float* k_b   = (const float*)d_in[2];
  const float* q_w   = (const float*)d_in[3];
  const float* q_b   = (const float*)d_in[4];
  const float* gp_w1 = (const float*)d_in[5];
  const float* gp_b1 = (const float*)d_in[6];
  const float* gp_w2 = (const float*)d_in[7];
  const float* gp_b2 = (const float*)d_in[8];
  const float* f_w   = (const float*)d_in[9];
  const float* f_b   = (const float*)d_in[10];
  float* out = (float*)d_out;

  float* ws  = (float*)d_ws;
  float* km  = ws;                                   // 2*32*3136 f32 (inner)
  float* qm  = km + (size_t)BB * CMM * LL;
  unsigned short* pre = (unsigned short*)(qm + (size_t)BB * CMM * LL); // bf16

  hipLaunchKernelGGL(kq_kernel, dim3(LL / 64, 1, BB), dim3(256), 0, stream,
                     x, k_w, k_b, q_w, q_b, km, qm);
  hipLaunchKernelGGL(attn_kernel, dim3(HH / 4, CMM, BB), dim3(256), 0, stream,
                     x, km, qm, gp_w1, gp_b1, gp_w2, gp_b2, k_b, pre);
  hipLaunchKernelGGL(fconv_kernel, dim3(LL / 64, CC / 64, BB), dim3(256), 0, stream,
                     pre, f_w, f_b, out);
}

// Round 18
// 43.638 us; speedup vs baseline: 6.6936x; 1.0069x over previous
//
#include <hip/hip_runtime.h>
#include <hip/hip_bf16.h>

#define CC 256
#define CMM 32
#define KW 7
#define KK 49
#define PADW 3
#define HH 56
#define WW 56
#define HP 62
#define LP 3844   // 62*62
#define LL 3136   // 56*56
#define BB 2
#define MM 8
#define MIDW 16

typedef __attribute__((ext_vector_type(8))) short bf16x8;
typedef __attribute__((ext_vector_type(4))) float f32x4;
typedef __attribute__((ext_vector_type(8))) unsigned short us8_t;
typedef __attribute__((ext_vector_type(4))) unsigned short us4_t;

__device__ inline short bfr(float f) {   // f32 -> bf16 bits, RNE
  unsigned int u = __builtin_bit_cast(unsigned int, f);
  u += 0x7fffu + ((u >> 16) & 1u);
  return (short)(u >> 16);
}
__device__ inline float bf2f(short h) {
  return __builtin_bit_cast(float, ((unsigned int)(unsigned short)h) << 16);
}
__device__ inline float ubits(unsigned int u) {
  return __builtin_bit_cast(float, u);
}

// ---------------- k/q 1x1 conv: 16-px tiles, single-phase MFMA --------------
// Grid (196, 1, 2) = 392 blocks. Stage 256c x 16px once (1 barrier), then
// 8 chunks x 2 (hi/lo) MFMA back-to-back. No double-buffer round trips.
__global__ void __launch_bounds__(256) kq_kernel(
    const float* __restrict__ x,
    const float* __restrict__ k_w, const float* __restrict__ k_b,
    const float* __restrict__ q_w, const float* __restrict__ q_b,
    float* __restrict__ km, float* __restrict__ qm) {
  __shared__ unsigned short bsT[16][264];   // [px][k], pad 264 u16/row
  int t = threadIdx.x;
  int lane = t & 63;
  int w = t >> 6;
  int px0 = blockIdx.x * 16;
  int b = blockIdx.z;
  int l15 = lane & 15;
  int hi = lane >> 4;

  // A-frags hi/lo: oc = w*16 + l15; k = s*32 + hi*8 + j
  int oc_a = w * 16 + l15;
  const float* wrow = ((oc_a < CMM) ? (k_w + (size_t)oc_a * CC)
                                    : (q_w + (size_t)(oc_a - CMM) * CC)) + hi * 8;
  bf16x8 ah[8], al[8];
  #pragma unroll
  for (int s = 0; s < 8; ++s) {
    f32x4 w0 = *(const f32x4*)(wrow + s * 32);
    f32x4 w1 = *(const f32x4*)(wrow + s * 32 + 4);
    bf16x8 h, l;
    #pragma unroll
    for (int j = 0; j < 4; ++j) {
      short hb0 = bfr(w0[j]); h[j] = hb0;     l[j] = bfr(w0[j] - bf2f(hb0));
      short hb1 = bfr(w1[j]); h[j + 4] = hb1; l[j + 4] = bfr(w1[j] - bf2f(hb1));
    }
    ah[s] = h; al[s] = l;
  }

  // single-phase staging: thread owns (px = t&15, c-block = (t>>4)*16)
  int spx = t & 15;
  int c0s = (t >> 4) * 16;
  const float* xg = x + (size_t)b * CC * LL + px0 + spx;
  float fv[16];
  #pragma unroll
  for (int j = 0; j < 16; ++j) fv[j] = xg[(size_t)(c0s + j) * LL];
  us8_t h0, h1;
  #pragma unroll
  for (int j = 0; j < 8; ++j) {
    h0[j] = (unsigned short)bfr(fv[j]);
    h1[j] = (unsigned short)bfr(fv[8 + j]);
  }
  *(us8_t*)&bsT[spx][c0s]     = h0;
  *(us8_t*)&bsT[spx][c0s + 8] = h1;
  __syncthreads();

  f32x4 acc = {0.f, 0.f, 0.f, 0.f};
  #pragma unroll
  for (int s = 0; s < 8; ++s) {
    bf16x8 bv = *(const bf16x8*)&bsT[l15][s * 32 + hi * 8];
    acc = __builtin_amdgcn_mfma_f32_16x16x32_bf16(ah[s], bv, acc, 0, 0, 0);
    acc = __builtin_amdgcn_mfma_f32_16x16x32_bf16(al[s], bv, acc, 0, 0, 0);
  }

  #pragma unroll
  for (int rr = 0; rr < 4; ++rr) {
    int oc = w * 16 + hi * 4 + rr;
    int px = px0 + l15;
    if (oc < CMM)
      km[((size_t)b * CMM + oc) * LL + px] = acc[rr] + k_b[oc];
    else
      qm[((size_t)b * CMM + (oc - CMM)) * LL + px] = acc[rr] + q_b[oc - CMM];
  }
}

// ---------------- fused QK * softmax * PV (R17, unchanged) ------------------
__global__ void __launch_bounds__(256) attn_kernel(
    const float* __restrict__ x, const float* __restrict__ km,
    const float* __restrict__ qm,
    const float* __restrict__ gp_w1, const float* __restrict__ gp_b1,
    const float* __restrict__ gp_w2, const float* __restrict__ gp_b2,
    const float* __restrict__ k_b,
    unsigned short* __restrict__ pre) {
  __shared__ unsigned int xlo[10][64][2];
  __shared__ unsigned int xhi[10][64][2];
  __shared__ float ks[10][64];
  __shared__ float gs2[KK];
  const float LOG2E = 1.44269504f;
  int t = threadIdx.x;
  int cm = blockIdx.y;
  int b = blockIdx.z;
  int y0 = blockIdx.x * 4;

  if (t < KK) {
    int i = t / KW, j = t % KW;
    float xpos = (float)(j - PADW), ypos = (float)(PADW - i);
    float a = gp_b2[cm];
    #pragma unroll
    for (int m = 0; m < MIDW; ++m) {
      float h = fmaxf(gp_w1[2 * m] * xpos + gp_w1[2 * m + 1] * ypos + gp_b1[m], 0.f);
      a = fmaf(gp_w2[cm * MIDW + m], h, a);
    }
    gs2[t] = a * LOG2E;
  }
  float kb_cm = k_b[cm];
  const float* kmb = km + ((size_t)b * CMM + cm) * LL;
  for (int e = t; e < 640; e += 256) {
    int ri = e >> 6, cl = e & 63;
    int rp = y0 + ri;
    bool inner = (rp >= PADW && rp < PADW + HH && cl >= PADW && cl < PADW + WW);
    ks[ri][cl] = inner ? kmb[(rp - PADW) * WW + (cl - PADW)] : kb_cm;
  }
  const float* xg = x + (size_t)b * CC * LL;
  for (int e = t; e < 640; e += 256) {
    int ri = e >> 6, cl = e & 63;
    int ir = y0 - PADW + ri;
    int ic = cl - PADW;
    bool ok = (ir >= 0 && ir < HH && ic >= 0 && ic < WW);
    int off = ok ? (ir * WW + ic) : 0;
    unsigned int pk[4];
    #pragma unroll
    for (int mp = 0; mp < 4; ++mp) {
      float v0 = ok ? xg[(size_t)((2 * mp) * CMM + cm) * LL + off] : 0.f;
      float v1 = ok ? xg[(size_t)((2 * mp + 1) * CMM + cm) * LL + off] : 0.f;
      pk[mp] = (unsigned int)(unsigned short)bfr(v0)
             | ((unsigned int)(unsigned short)bfr(v1) << 16);
    }
    *(uint2*)&xlo[ri][cl][0] = make_uint2(pk[0], pk[1]);
    *(uint2*)&xhi[ri][cl][0] = make_uint2(pk[2], pk[3]);
  }
  __syncthreads();

  int w = t >> 6, c = t & 63;
  int y = y0 + w;
  int ce = (c < WW) ? c : (WW - 1);
  bool act = (c < WW);
  float qc = qm[((size_t)b * CMM + cm) * LL + y * WW + ce] * LOG2E;

  float acc[8] = {0.f, 0.f, 0.f, 0.f, 0.f, 0.f, 0.f, 0.f};
  #pragma unroll
  for (int i = 0; i < KW; ++i) {
    int row = w + i;
    float s[KW];
    float sum = 0.f;
    #pragma unroll
    for (int j = 0; j < KW; ++j) {
      s[j] = exp2f(fmaf(ks[row][ce + j], qc, gs2[i * KW + j]));
      sum += s[j];
    }
    float inv = __builtin_amdgcn_rcpf(sum);
    #pragma unroll
    for (int j = 0; j < KW; ++j) {
      float wj = s[j] * inv;
      uint2 lo2 = *(const uint2*)&xlo[row][ce + j][0];
      uint2 hi2 = *(const uint2*)&xhi[row][ce + j][0];
      acc[0] = fmaf(wj, ubits(lo2.x << 16), acc[0]);
      acc[1] = fmaf(wj, ubits(lo2.x & 0xffff0000u), acc[1]);
      acc[2] = fmaf(wj, ubits(lo2.y << 16), acc[2]);
      acc[3] = fmaf(wj, ubits(lo2.y & 0xffff0000u), acc[3]);
      acc[4] = fmaf(wj, ubits(hi2.x << 16), acc[4]);
      acc[5] = fmaf(wj, ubits(hi2.x & 0xffff0000u), acc[5]);
      acc[6] = fmaf(wj, ubits(hi2.y << 16), acc[6]);
      acc[7] = fmaf(wj, ubits(hi2.y & 0xffff0000u), acc[7]);
    }
  }
  if (act) {
    #pragma unroll
    for (int m = 0; m < 8; ++m)
      pre[((size_t)b * CC + (m * CMM + cm)) * LL + y * WW + c] =
          (unsigned short)bfr(acc[m]);
  }
}

// ---------------- final 1x1 conv: 32-px tiles, single-phase MFMA ------------
// Grid (98, 4, 2) = 784 blocks. Stage 256c x 32px bf16 once, 1 barrier,
// 16 MFMA per wave.
__global__ void __launch_bounds__(256) fconv_kernel(
    const unsigned short* __restrict__ preb,
    const float* __restrict__ f_w, const float* __restrict__ f_b,
    float* __restrict__ out) {
  __shared__ unsigned short bsT[32][264];
  int t = threadIdx.x;
  int lane = t & 63;
  int w = t >> 6;
  int px0 = blockIdx.x * 32;
  int oc0 = blockIdx.y * 64;
  int b = blockIdx.z;
  int l15 = lane & 15;
  int hi = lane >> 4;

  bf16x8 af[8];
  const float* wrow = f_w + (size_t)(oc0 + w * 16 + l15) * CC + hi * 8;
  #pragma unroll
  for (int s = 0; s < 8; ++s) {
    f32x4 w0 = *(const f32x4*)(wrow + s * 32);
    f32x4 w1 = *(const f32x4*)(wrow + s * 32 + 4);
    bf16x8 a;
    #pragma unroll
    for (int j = 0; j < 4; ++j) { a[j] = bfr(w0[j]); a[j + 4] = bfr(w1[j]); }
    af[s] = a;
  }

  // single-phase staging: thread owns (px = t&31, c-block = (t>>5)*32)
  int spx = t & 31;
  int c0s = (t >> 5) * 32;
  const unsigned short* pg = preb + (size_t)b * CC * LL + px0 + spx;
  unsigned short uv[32];
  #pragma unroll
  for (int j = 0; j < 32; ++j) uv[j] = pg[(size_t)(c0s + j) * LL];
  #pragma unroll
  for (int qq = 0; qq < 4; ++qq) {
    us8_t hv;
    #pragma unroll
    for (int j = 0; j < 8; ++j) hv[j] = uv[qq * 8 + j];
    *(us8_t*)&bsT[spx][c0s + qq * 8] = hv;
  }
  __syncthreads();

  f32x4 acc[2];
  #pragma unroll
  for (int q = 0; q < 2; ++q) acc[q] = {0.f, 0.f, 0.f, 0.f};
  #pragma unroll
  for (int s = 0; s < 8; ++s) {
    #pragma unroll
    for (int q = 0; q < 2; ++q) {
      bf16x8 bv = *(const bf16x8*)&bsT[q * 16 + l15][s * 32 + hi * 8];
      acc[q] = __builtin_amdgcn_mfma_f32_16x16x32_bf16(af[s], bv, acc[q], 0, 0, 0);
    }
  }

  #pragma unroll
  for (int q = 0; q < 2; ++q) {
    #pragma unroll
    for (int rr = 0; rr < 4; ++rr) {
      int oc = oc0 + w * 16 + hi * 4 + rr;
      out[((size_t)b * CC + oc) * LL + px0 + q * 16 + l15] = acc[q][rr] + f_b[oc];
    }
  }
}

extern "C" void kernel_launch(void* const* d_in, const int* in_sizes, int n_in,
                              void* d_out, int out_size, void* d_ws, size_t ws_size,
                              hipStream_t stream) {
  const float* x     = (const float*)d_in[0];
  const float* k_w   = (const float*)d_in[1];
  const float* k_b   = (const float*)d_in[2];
  const float* q_w   = (const float*)d_in[3];
  const float* q_b   = (const float*)d_in[4];
  const float* gp_w1 = (const float*)d_in[5];
  const float* gp_b1 = (const float*)d_in[6];
  const float* gp_w2 = (const float*)d_in[7];
  const float* gp_b2 = (const float*)d_in[8];
  const float* f_w   = (const float*)d_in[9];
  const float* f_b   = (const float*)d_in[10];
  float* out = (float*)d_out;

  float* ws  = (float*)d_ws;
  float* km  = ws;                                   // 2*32*3136 f32 (inner)
  float* qm  = km + (size_t)BB * CMM * LL;
  unsigned short* pre = (unsigned short*)(qm + (size_t)BB * CMM * LL); // bf16

  hipLaunchKernelGGL(kq_kernel, dim3(LL / 16, 1, BB), dim3(256), 0, stream,
                     x, k_w, k_b, q_w, q_b, km, qm);
  hipLaunchKernelGGL(attn_kernel, dim3(HH / 4, CMM, BB), dim3(256), 0, stream,
                     x, km, qm, gp_w1, gp_b1, gp_w2, gp_b2, k_b, pre);
  hipLaunchKernelGGL(fconv_kernel, dim3(LL / 32, CC / 64, BB), dim3(256), 0, stream,
                     pre, f_w, f_b, out);
}